// Round 11
// baseline (74.470 us; speedup 1.0000x reference)
//
#include <hip/hip_runtime.h>
#include <hip/hip_bf16.h>
#include <math.h>

// Problem constants (reference: BATCH=2048, D=256, TEMP=0.5)
#define NB        2048
#define TWO_N     4096
#define DIM       256
#define EPS       1e-12f
#define NT1D      (TWO_N / 128)                 // 32 tile rows/cols
#define NTILES    (NT1D * (NT1D + 1) / 2)       // 528 upper-triangle tiles

// z storage: FRAGMENT-MAJOR tiled layout (r6). For row R, element e:
//   short_idx = (R>>4)*4096 + (e>>5)*512 + ((e>>3)&3)*128 + (R&15)*8 + (e&7)
// A (row-block RB, K-step s) fragment piece = 1 KB contiguous at
// RB*4096 + s*512; lane l's 16 B at +l*8 shorts.

typedef __attribute__((ext_vector_type(8))) short  bf16x8;   // 8 bf16 = 4 VGPRs
typedef __attribute__((ext_vector_type(4))) float  f32x4;    // MFMA C/D

// ---------------------------------------------------------------------------
// K1: one wave per PAIR r in [0,2048): L2-normalize emb_i[r] -> z[r] and
// emb_j[r] -> z[r+NB] (bf16, fragment-major layout), and write the
// fp32-exact positive dot pos[r] = <z_i, z_j>. Also zeroes the output.
// ---------------------------------------------------------------------------
__global__ __launch_bounds__(256) void nrm_kernel(
    const float* __restrict__ emb_i, const float* __restrict__ emb_j,
    short* __restrict__ zt, float* __restrict__ pos,
    float* __restrict__ out)
{
    int t = threadIdx.x;
    int wave = t >> 6, lane = t & 63;
    int r = blockIdx.x * 4 + wave;              // pair index 0..2047
    float4 a = ((const float4*)(emb_i + (size_t)r * DIM))[lane];
    float4 b = ((const float4*)(emb_j + (size_t)r * DIM))[lane];
    float sa = a.x*a.x + a.y*a.y + a.z*a.z + a.w*a.w;
    float sb = b.x*b.x + b.y*b.y + b.z*b.z + b.w*b.w;
    float sd = a.x*b.x + a.y*b.y + a.z*b.z + a.w*b.w;
    #pragma unroll
    for (int off = 32; off >= 1; off >>= 1) {
        sa += __shfl_xor(sa, off, 64);
        sb += __shfl_xor(sb, off, 64);
        sd += __shfl_xor(sd, off, 64);
    }
    float si = 1.0f / fmaxf(sqrtf(sa), EPS);
    float sj = 1.0f / fmaxf(sqrtf(sb), EPS);

    int dst = (r >> 4) * 4096 + (lane >> 3) * 512 + ((lane >> 1) & 3) * 128
            + (r & 15) * 8 + (lane & 1) * 4;

    union { __hip_bfloat16 h[4]; uint2 u; } pk;
    pk.h[0] = __float2bfloat16(a.x * si);
    pk.h[1] = __float2bfloat16(a.y * si);
    pk.h[2] = __float2bfloat16(a.z * si);
    pk.h[3] = __float2bfloat16(a.w * si);
    *(uint2*)(zt + dst) = pk.u;                       // z_i row r
    pk.h[0] = __float2bfloat16(b.x * sj);
    pk.h[1] = __float2bfloat16(b.y * sj);
    pk.h[2] = __float2bfloat16(b.z * sj);
    pk.h[3] = __float2bfloat16(b.w * sj);
    *(uint2*)(zt + dst + 128 * 4096) = pk.u;          // z_j row r+2048

    if (lane == 0) pos[r] = sd * si * sj;
    if (blockIdx.x == 0 && t == 0) out[0] = 0.0f;     // loss accumulator
}

// ---------------------------------------------------------------------------
// K2: bf16 MFMA over the 528 upper-triangle 128x128 tiles, LDS-STAGED.
// r10: K-chunk 32, 2x16 KB dbuf, (256,3) -> single generation.  r11 CHANGE:
// DEFERRED-WRITE pipeline. r10 gave each SLD only one COMPUTE (~250 cyc) to
// cover ~400-900 cyc load latency -> per-chunk stall at DSW's vmcnt wait.
// Now chunk c = { DSW(set loaded during chunk c-1)  <- full chunk of slack
//                 SLD(c+2) into the just-freed set
//                 COMPUTE(c) ; barrier }
// LDS safety: buf((c+1)&1) holds chunk c-1, fully consumed before the
// barrier that opened chunk c -> writable during chunk c.  Two named G-sets
// (GA*, GB*) alternate. Same bytes -> same MFMA order -> bit-identical.
// VGPR: acc 64 + GA/GB 32 + frag temps ~32 + addr ~16 = ~145 < 170 cap.
// part[] slot scheme unchanged (round-2 comment).
// Fragment layouts (verified m89/m91): A[m=lane&15][k=quad*8+j],
// B[k=quad*8+j][n=lane&15], C/D: col=lane&15, row=quad*4+reg.
// ---------------------------------------------------------------------------
#define MFMA1(Av, Bv, m, n) \
    acc[m][n] = __builtin_amdgcn_mfma_f32_16x16x32_bf16(Av, Bv, acc[m][n], 0, 0, 0);

#define MFMA_ROW(Av, B0v, B1v, B2v, B3v, m) \
    MFMA1(Av, B0v, m, 0) MFMA1(Av, B1v, m, 1) \
    MFMA1(Av, B2v, m, 2) MFMA1(Av, B3v, m, 3)

#define MMSTEP(A0v, A1v, A2v, A3v, B0v, B1v, B2v, B3v) \
    MFMA_ROW(A0v, B0v, B1v, B2v, B3v, 0) \
    MFMA_ROW(A1v, B0v, B1v, B2v, B3v, 1) \
    MFMA_ROW(A2v, B0v, B1v, B2v, B3v, 2) \
    MFMA_ROW(A3v, B0v, B1v, B2v, B3v, 3)

#define SB __builtin_amdgcn_sched_barrier(0);

// Stage chunk c's 4 pieces into G-set X (A or B).
#define SLDX(X, c) \
    G##X##0 = *(const bf16x8*)(stg_base + 0 * 4096 + (c) * 512); \
    G##X##1 = *(const bf16x8*)(stg_base + 1 * 4096 + (c) * 512); \
    G##X##2 = *(const bf16x8*)(stg_base + 2 * 4096 + (c) * 512); \
    G##X##3 = *(const bf16x8*)(stg_base + 3 * 4096 + (c) * 512);

// Write G-set X to LDS buffer bs (wave's 4 pieces at p0 = w*4).
#define DSWX(X, bs) \
    *(bf16x8*)&lds[(bs)*8192 + (p0+0)*512 + l8] = G##X##0; \
    *(bf16x8*)&lds[(bs)*8192 + (p0+1)*512 + l8] = G##X##1; \
    *(bf16x8*)&lds[(bs)*8192 + (p0+2)*512 + l8] = G##X##2; \
    *(bf16x8*)&lds[(bs)*8192 + (p0+3)*512 + l8] = G##X##3;

// One K-step from chunk buffer bs: 8 ds_read_b128 + 16 MFMA.
#define COMPUTE(bs) \
    { \
        bf16x8 fa0 = *(const bf16x8*)&lds[(bs)*8192 + (wm4+0)*512 + l8]; \
        bf16x8 fa1 = *(const bf16x8*)&lds[(bs)*8192 + (wm4+1)*512 + l8]; \
        bf16x8 fa2 = *(const bf16x8*)&lds[(bs)*8192 + (wm4+2)*512 + l8]; \
        bf16x8 fa3 = *(const bf16x8*)&lds[(bs)*8192 + (wm4+3)*512 + l8]; \
        bf16x8 fb0 = *(const bf16x8*)&lds[(bs)*8192 + 4096 + (wn4+0)*512 + l8]; \
        bf16x8 fb1 = *(const bf16x8*)&lds[(bs)*8192 + 4096 + (wn4+1)*512 + l8]; \
        bf16x8 fb2 = *(const bf16x8*)&lds[(bs)*8192 + 4096 + (wn4+2)*512 + l8]; \
        bf16x8 fb3 = *(const bf16x8*)&lds[(bs)*8192 + 4096 + (wn4+3)*512 + l8]; \
        MMSTEP(fa0, fa1, fa2, fa3, fb0, fb1, fb2, fb3) \
    }

__global__ __launch_bounds__(256, 3) void simexp_kernel(
    const short* __restrict__ zt, float* __restrict__ part)
{
    __shared__ short lds[2 * 8192];             // 2 x 16 KB chunk buffers

    // Decode linear triangle index -> (bx, by), bx <= by.
    int id = blockIdx.x;
    int by = (int)((sqrtf(8.0f * (float)id + 1.0f) - 1.0f) * 0.5f);
    while ((by + 1) * (by + 2) / 2 <= id) ++by;   // fix float rounding
    while (by * (by + 1) / 2 > id) --by;
    int bx = id - by * (by + 1) / 2;

    int t = threadIdx.x;
    int w = t >> 6, lane = t & 63;
    int quad = lane >> 4, c16 = lane & 15;
    int wm = w >> 1, wn = w & 1;
    int wm4 = wm * 4, wn4 = wn * 4;
    int l8 = lane * 8;
    int p0 = w * 4;
    int rbase = bx * 128 + wm * 64;
    int jbase = by * 128 + wn * 64;

    // Staging source: waves 0,1 -> A panel (row-blocks bx*8 + {0-3,4-7});
    // waves 2,3 -> B panel (by*8 + {0-3,4-7}).
    const short* stg_base = zt
        + (size_t)((w < 2 ? bx : by) * 8 + (w & 1) * 4) * 4096 + l8;

    f32x4 acc[4][4];
    #pragma unroll
    for (int mt = 0; mt < 4; ++mt)
        #pragma unroll
        for (int nt = 0; nt < 4; ++nt)
            acc[mt][nt] = (f32x4){0.f, 0.f, 0.f, 0.f};

    bf16x8 GA0, GA1, GA2, GA3;   // even-distance set
    bf16x8 GB0, GB1, GB2, GB3;   // odd-distance set

    // Prologue: chunk 0 via set A; issue chunk 1 (set B) before the barrier.
    SLDX(A, 0)
    DSWX(A, 0)
    SLDX(B, 1)
    __syncthreads();
    // chunk 0: issue c2 into freed A; compute c0; write c1 late (r10-style
    // slack for B only this once).
    SLDX(A, 2) SB
    COMPUTE(0) SB
    DSWX(B, 1)
    __syncthreads();
    // chunk 1: write c2 (A, full-chunk slack); issue c3 into freed... B was
    // just written -> B free; compute c1.
    DSWX(A, 0) SB
    SLDX(B, 3) SB
    COMPUTE(1)
    __syncthreads();
    // chunk 2
    DSWX(B, 1) SB
    SLDX(A, 4) SB
    COMPUTE(0)
    __syncthreads();
    // chunk 3
    DSWX(A, 0) SB
    SLDX(B, 5) SB
    COMPUTE(1)
    __syncthreads();
    // chunk 4
    DSWX(B, 1) SB
    SLDX(A, 6) SB
    COMPUTE(0)
    __syncthreads();
    // chunk 5
    DSWX(A, 0) SB
    SLDX(B, 7) SB
    COMPUTE(1)
    __syncthreads();
    // chunk 6
    DSWX(B, 1) SB
    COMPUTE(0)
    __syncthreads();
    // chunk 7
    COMPUTE(1)

    // Epilogue. Row of acc[mt][nt][rg] = rbase+mt*16+quad*4+rg,
    // col = jbase+nt*16+c16.
    float rsum[4][4];
    #pragma unroll
    for (int mt = 0; mt < 4; ++mt)
        #pragma unroll
        for (int rg = 0; rg < 4; ++rg) rsum[mt][rg] = 0.f;

    if (bx == by) {
        #pragma unroll
        for (int mt = 0; mt < 4; ++mt) {
            #pragma unroll
            for (int nt = 0; nt < 4; ++nt) {
                int j = jbase + nt * 16 + c16;
                #pragma unroll
                for (int rg = 0; rg < 4; ++rg) {
                    int r = rbase + mt * 16 + quad * 4 + rg;
                    float e = __expf(2.0f * acc[mt][nt][rg]);
                    rsum[mt][rg] += (r == j) ? 0.f : e;
                }
            }
        }
    } else {
        float csum[4] = {0.f, 0.f, 0.f, 0.f};
        #pragma unroll
        for (int mt = 0; mt < 4; ++mt) {
            #pragma unroll
            for (int nt = 0; nt < 4; ++nt) {
                #pragma unroll
                for (int rg = 0; rg < 4; ++rg) {
                    float e = __expf(2.0f * acc[mt][nt][rg]);
                    rsum[mt][rg] += e;
                    csum[nt] += e;
                }
            }
        }
        #pragma unroll
        for (int nt = 0; nt < 4; ++nt) {
            float v = csum[nt];
            v += __shfl_xor(v, 16, 64);
            v += __shfl_xor(v, 32, 64);
            if (quad == 0)
                part[(size_t)(by * 128 + wn * 64 + nt * 16 + c16) * 64
                     + 2 * bx + wm] = v;
        }
    }

    #pragma unroll
    for (int mt = 0; mt < 4; ++mt) {
        #pragma unroll
        for (int rg = 0; rg < 4; ++rg) {
            float v = rsum[mt][rg];
            v += __shfl_xor(v, 1, 64);
            v += __shfl_xor(v, 2, 64);
            v += __shfl_xor(v, 4, 64);
            v += __shfl_xor(v, 8, 64);
            if (c16 == 0)
                part[(size_t)(rbase + mt * 16 + quad * 4 + rg) * 64
                     + 2 * by + wn] = v;
        }
    }
}

// ---------------------------------------------------------------------------
// K3: 32 blocks x 128 threads. Block s, thread t owns row r = s*128+t:
// den_r = sum of its 64 partials (256 B contiguous), then
// loss_r = log(den_r) - 2*pos[r mod 2048]. Block-reduce, one atomicAdd of
// the scaled partial into out[0] (32 atomics total; out zeroed by K1).
// ---------------------------------------------------------------------------
__global__ __launch_bounds__(128) void redloss_kernel(
    const float* __restrict__ part, const float* __restrict__ pos,
    float* __restrict__ out)
{
    int s = blockIdx.x, t = threadIdx.x;
    int r = s * 128 + t;
    const float4* p = (const float4*)(part + ((size_t)r << 6));
    float sum = 0.f;
    #pragma unroll
    for (int i = 0; i < 16; ++i) {
        float4 v = p[i];
        sum += v.x + v.y + v.z + v.w;
    }
    float val = logf(sum) - 2.0f * pos[r & (NB - 1)];
    #pragma unroll
    for (int off = 32; off >= 1; off >>= 1) val += __shfl_xor(val, off, 64);
    __shared__ float red[2];
    if ((t & 63) == 0) red[t >> 6] = val;
    __syncthreads();
    if (t == 0)
        atomicAdd(out, (red[0] + red[1]) * (1.0f / (float)TWO_N));
}

// ---------------------------------------------------------------------------
extern "C" void kernel_launch(void* const* d_in, const int* in_sizes, int n_in,
                              void* d_out, int out_size, void* d_ws, size_t ws_size,
                              hipStream_t stream)
{
    const float* emb_i = (const float*)d_in[0];
    const float* emb_j = (const float*)d_in[1];
    float* out = (float*)d_out;

    short* zt = (short*)d_ws;                             // 4096*256 bf16 = 2 MB (tiled)
    float* part = (float*)((char*)d_ws + (size_t)TWO_N * DIM * sizeof(short));
    // part: 4096 rows x 64 partials = 1 MB
    float* pos = part + (size_t)TWO_N * 64;               // 2048 f32

    nrm_kernel<<<NB / 4, 256, 0, stream>>>(emb_i, emb_j, zt, pos, out);
    simexp_kernel<<<NTILES, 256, 0, stream>>>(zt, part);
    redloss_kernel<<<NT1D, 128, 0, stream>>>(part, pos, out);
}

// Round 12
// 74.438 us; speedup vs baseline: 1.0004x; 1.0004x over previous
//
#include <hip/hip_runtime.h>
#include <hip/hip_bf16.h>
#include <math.h>

// Problem constants (reference: BATCH=2048, D=256, TEMP=0.5)
#define NB        2048
#define TWO_N     4096
#define DIM       256
#define EPS       1e-12f
#define NT1D      (TWO_N / 128)                 // 32 tile rows/cols
#define NTILES    (NT1D * (NT1D + 1) / 2)       // 528 upper-triangle tiles

// z storage: FRAGMENT-MAJOR tiled layout (r6). For row R, element e:
//   short_idx = (R>>4)*4096 + (e>>5)*512 + ((e>>3)&3)*128 + (R&15)*8 + (e&7)
// A (row-block RB, K-step s) fragment piece = 1 KB contiguous at
// RB*4096 + s*512; lane l's 16 B at +l*8 shorts.

typedef __attribute__((ext_vector_type(8))) short  bf16x8;   // 8 bf16 = 4 VGPRs
typedef __attribute__((ext_vector_type(4))) float  f32x4;    // MFMA C/D

// ---------------------------------------------------------------------------
// K1: one wave per PAIR r in [0,2048): L2-normalize emb_i[r] -> z[r] and
// emb_j[r] -> z[r+NB] (bf16, fragment-major layout), and write the
// fp32-exact positive dot pos[r] = <z_i, z_j>. Also zeroes the output.
// ---------------------------------------------------------------------------
__global__ __launch_bounds__(256) void nrm_kernel(
    const float* __restrict__ emb_i, const float* __restrict__ emb_j,
    short* __restrict__ zt, float* __restrict__ pos,
    float* __restrict__ out)
{
    int t = threadIdx.x;
    int wave = t >> 6, lane = t & 63;
    int r = blockIdx.x * 4 + wave;              // pair index 0..2047
    float4 a = ((const float4*)(emb_i + (size_t)r * DIM))[lane];
    float4 b = ((const float4*)(emb_j + (size_t)r * DIM))[lane];
    float sa = a.x*a.x + a.y*a.y + a.z*a.z + a.w*a.w;
    float sb = b.x*b.x + b.y*b.y + b.z*b.z + b.w*b.w;
    float sd = a.x*b.x + a.y*b.y + a.z*b.z + a.w*b.w;
    #pragma unroll
    for (int off = 32; off >= 1; off >>= 1) {
        sa += __shfl_xor(sa, off, 64);
        sb += __shfl_xor(sb, off, 64);
        sd += __shfl_xor(sd, off, 64);
    }
    float si = 1.0f / fmaxf(sqrtf(sa), EPS);
    float sj = 1.0f / fmaxf(sqrtf(sb), EPS);

    int dst = (r >> 4) * 4096 + (lane >> 3) * 512 + ((lane >> 1) & 3) * 128
            + (r & 15) * 8 + (lane & 1) * 4;

    union { __hip_bfloat16 h[4]; uint2 u; } pk;
    pk.h[0] = __float2bfloat16(a.x * si);
    pk.h[1] = __float2bfloat16(a.y * si);
    pk.h[2] = __float2bfloat16(a.z * si);
    pk.h[3] = __float2bfloat16(a.w * si);
    *(uint2*)(zt + dst) = pk.u;                       // z_i row r
    pk.h[0] = __float2bfloat16(b.x * sj);
    pk.h[1] = __float2bfloat16(b.y * sj);
    pk.h[2] = __float2bfloat16(b.z * sj);
    pk.h[3] = __float2bfloat16(b.w * sj);
    *(uint2*)(zt + dst + 128 * 4096) = pk.u;          // z_j row r+2048

    if (lane == 0) pos[r] = sd * si * sj;
    if (blockIdx.x == 0 && t == 0) out[0] = 0.0f;     // loss accumulator
}

// ---------------------------------------------------------------------------
// K2: bf16 MFMA over the 528 upper-triangle 128x128 tiles, LDS-STAGED.
// r10: K-chunk 32, 2x16 KB dbuf, (256,3), single generation.
// r11: deferred-write pipeline (DSW of a set one full chunk after its SLD).
// r12 CHANGE (T4, the enabler r11 was missing): __syncthreads() lowers to
// `s_waitcnt vmcnt(0) lgkmcnt(0); s_barrier` — the vmcnt(0) drains ALL
// in-flight prefetch loads at EVERY chunk barrier, nullifying r11's
// deferral (r10 == r11 measured). Replace every barrier with
//   { s_waitcnt lgkmcnt(0) (asm) ; raw s_barrier }   — NO vmcnt drain.
// Correctness: lgkmcnt(0) per-wave retires all its ds_reads (WAR vs next
// chunk's writes) and ds_writes (RAW visibility; LDS is CU-local) before
// the barrier. Global loads feed only the issuing wave's registers; the
// compiler still emits counted vmcnt before each DSW's ds_writes — by
// then the G-set is a full chunk old -> wait ~0. No cross-wave global
// hazards until the epilogue (after the last barrier).
// Same bytes -> same MFMA order -> bit-identical accumulators.
// part[] slot scheme unchanged (round-2 comment).
// Fragment layouts (verified m89/m91): A[m=lane&15][k=quad*8+j],
// B[k=quad*8+j][n=lane&15], C/D: col=lane&15, row=quad*4+reg.
// ---------------------------------------------------------------------------
#define MFMA1(Av, Bv, m, n) \
    acc[m][n] = __builtin_amdgcn_mfma_f32_16x16x32_bf16(Av, Bv, acc[m][n], 0, 0, 0);

#define MFMA_ROW(Av, B0v, B1v, B2v, B3v, m) \
    MFMA1(Av, B0v, m, 0) MFMA1(Av, B1v, m, 1) \
    MFMA1(Av, B2v, m, 2) MFMA1(Av, B3v, m, 3)

#define MMSTEP(A0v, A1v, A2v, A3v, B0v, B1v, B2v, B3v) \
    MFMA_ROW(A0v, B0v, B1v, B2v, B3v, 0) \
    MFMA_ROW(A1v, B0v, B1v, B2v, B3v, 1) \
    MFMA_ROW(A2v, B0v, B1v, B2v, B3v, 2) \
    MFMA_ROW(A3v, B0v, B1v, B2v, B3v, 3)

#define SB __builtin_amdgcn_sched_barrier(0);

// Raw barrier: LDS-drain only (no vmcnt drain). Rule-#18 fence via SB.
#define BAR \
    SB \
    asm volatile("s_waitcnt lgkmcnt(0)" ::: "memory"); \
    SB \
    __builtin_amdgcn_s_barrier(); \
    SB

// Stage chunk c's 4 pieces into G-set X (A or B).
#define SLDX(X, c) \
    G##X##0 = *(const bf16x8*)(stg_base + 0 * 4096 + (c) * 512); \
    G##X##1 = *(const bf16x8*)(stg_base + 1 * 4096 + (c) * 512); \
    G##X##2 = *(const bf16x8*)(stg_base + 2 * 4096 + (c) * 512); \
    G##X##3 = *(const bf16x8*)(stg_base + 3 * 4096 + (c) * 512);

// Write G-set X to LDS buffer bs (wave's 4 pieces at p0 = w*4).
#define DSWX(X, bs) \
    *(bf16x8*)&lds[(bs)*8192 + (p0+0)*512 + l8] = G##X##0; \
    *(bf16x8*)&lds[(bs)*8192 + (p0+1)*512 + l8] = G##X##1; \
    *(bf16x8*)&lds[(bs)*8192 + (p0+2)*512 + l8] = G##X##2; \
    *(bf16x8*)&lds[(bs)*8192 + (p0+3)*512 + l8] = G##X##3;

// One K-step from chunk buffer bs: 8 ds_read_b128 + 16 MFMA.
#define COMPUTE(bs) \
    { \
        bf16x8 fa0 = *(const bf16x8*)&lds[(bs)*8192 + (wm4+0)*512 + l8]; \
        bf16x8 fa1 = *(const bf16x8*)&lds[(bs)*8192 + (wm4+1)*512 + l8]; \
        bf16x8 fa2 = *(const bf16x8*)&lds[(bs)*8192 + (wm4+2)*512 + l8]; \
        bf16x8 fa3 = *(const bf16x8*)&lds[(bs)*8192 + (wm4+3)*512 + l8]; \
        bf16x8 fb0 = *(const bf16x8*)&lds[(bs)*8192 + 4096 + (wn4+0)*512 + l8]; \
        bf16x8 fb1 = *(const bf16x8*)&lds[(bs)*8192 + 4096 + (wn4+1)*512 + l8]; \
        bf16x8 fb2 = *(const bf16x8*)&lds[(bs)*8192 + 4096 + (wn4+2)*512 + l8]; \
        bf16x8 fb3 = *(const bf16x8*)&lds[(bs)*8192 + 4096 + (wn4+3)*512 + l8]; \
        MMSTEP(fa0, fa1, fa2, fa3, fb0, fb1, fb2, fb3) \
    }

__global__ __launch_bounds__(256, 3) void simexp_kernel(
    const short* __restrict__ zt, float* __restrict__ part)
{
    __shared__ short lds[2 * 8192];             // 2 x 16 KB chunk buffers

    // Decode linear triangle index -> (bx, by), bx <= by.
    int id = blockIdx.x;
    int by = (int)((sqrtf(8.0f * (float)id + 1.0f) - 1.0f) * 0.5f);
    while ((by + 1) * (by + 2) / 2 <= id) ++by;   // fix float rounding
    while (by * (by + 1) / 2 > id) --by;
    int bx = id - by * (by + 1) / 2;

    int t = threadIdx.x;
    int w = t >> 6, lane = t & 63;
    int quad = lane >> 4, c16 = lane & 15;
    int wm = w >> 1, wn = w & 1;
    int wm4 = wm * 4, wn4 = wn * 4;
    int l8 = lane * 8;
    int p0 = w * 4;
    int rbase = bx * 128 + wm * 64;
    int jbase = by * 128 + wn * 64;

    // Staging source: waves 0,1 -> A panel (row-blocks bx*8 + {0-3,4-7});
    // waves 2,3 -> B panel (by*8 + {0-3,4-7}).
    const short* stg_base = zt
        + (size_t)((w < 2 ? bx : by) * 8 + (w & 1) * 4) * 4096 + l8;

    f32x4 acc[4][4];
    #pragma unroll
    for (int mt = 0; mt < 4; ++mt)
        #pragma unroll
        for (int nt = 0; nt < 4; ++nt)
            acc[mt][nt] = (f32x4){0.f, 0.f, 0.f, 0.f};

    bf16x8 GA0, GA1, GA2, GA3;   // even-distance set
    bf16x8 GB0, GB1, GB2, GB3;   // odd-distance set

    // Prologue: chunk 0 via set A; issue chunk 1 (set B) before the barrier.
    SLDX(A, 0)
    DSWX(A, 0)
    SLDX(B, 1)
    BAR
    // chunk 0
    SLDX(A, 2) SB
    COMPUTE(0) SB
    DSWX(B, 1)
    BAR
    // chunk 1: DSW(A=c2) now has had COMPUTE(0)+DSW(B)+barrier of cover,
    // and with no vmcnt drain at BAR the A-loads stayed in flight.
    DSWX(A, 0) SB
    SLDX(B, 3) SB
    COMPUTE(1)
    BAR
    // chunk 2
    DSWX(B, 1) SB
    SLDX(A, 4) SB
    COMPUTE(0)
    BAR
    // chunk 3
    DSWX(A, 0) SB
    SLDX(B, 5) SB
    COMPUTE(1)
    BAR
    // chunk 4
    DSWX(B, 1) SB
    SLDX(A, 6) SB
    COMPUTE(0)
    BAR
    // chunk 5
    DSWX(A, 0) SB
    SLDX(B, 7) SB
    COMPUTE(1)
    BAR
    // chunk 6
    DSWX(B, 1) SB
    COMPUTE(0)
    BAR
    // chunk 7
    COMPUTE(1)

    // Epilogue. Row of acc[mt][nt][rg] = rbase+mt*16+quad*4+rg,
    // col = jbase+nt*16+c16.
    float rsum[4][4];
    #pragma unroll
    for (int mt = 0; mt < 4; ++mt)
        #pragma unroll
        for (int rg = 0; rg < 4; ++rg) rsum[mt][rg] = 0.f;

    if (bx == by) {
        #pragma unroll
        for (int mt = 0; mt < 4; ++mt) {
            #pragma unroll
            for (int nt = 0; nt < 4; ++nt) {
                int j = jbase + nt * 16 + c16;
                #pragma unroll
                for (int rg = 0; rg < 4; ++rg) {
                    int r = rbase + mt * 16 + quad * 4 + rg;
                    float e = __expf(2.0f * acc[mt][nt][rg]);
                    rsum[mt][rg] += (r == j) ? 0.f : e;
                }
            }
        }
    } else {
        float csum[4] = {0.f, 0.f, 0.f, 0.f};
        #pragma unroll
        for (int mt = 0; mt < 4; ++mt) {
            #pragma unroll
            for (int nt = 0; nt < 4; ++nt) {
                #pragma unroll
                for (int rg = 0; rg < 4; ++rg) {
                    float e = __expf(2.0f * acc[mt][nt][rg]);
                    rsum[mt][rg] += e;
                    csum[nt] += e;
                }
            }
        }
        #pragma unroll
        for (int nt = 0; nt < 4; ++nt) {
            float v = csum[nt];
            v += __shfl_xor(v, 16, 64);
            v += __shfl_xor(v, 32, 64);
            if (quad == 0)
                part[(size_t)(by * 128 + wn * 64 + nt * 16 + c16) * 64
                     + 2 * bx + wm] = v;
        }
    }

    #pragma unroll
    for (int mt = 0; mt < 4; ++mt) {
        #pragma unroll
        for (int rg = 0; rg < 4; ++rg) {
            float v = rsum[mt][rg];
            v += __shfl_xor(v, 1, 64);
            v += __shfl_xor(v, 2, 64);
            v += __shfl_xor(v, 4, 64);
            v += __shfl_xor(v, 8, 64);
            if (c16 == 0)
                part[(size_t)(rbase + mt * 16 + quad * 4 + rg) * 64
                     + 2 * by + wn] = v;
        }
    }
}

// ---------------------------------------------------------------------------
// K3: 32 blocks x 128 threads. Block s, thread t owns row r = s*128+t:
// den_r = sum of its 64 partials (256 B contiguous), then
// loss_r = log(den_r) - 2*pos[r mod 2048]. Block-reduce, one atomicAdd of
// the scaled partial into out[0] (32 atomics total; out zeroed by K1).
// ---------------------------------------------------------------------------
__global__ __launch_bounds__(128) void redloss_kernel(
    const float* __restrict__ part, const float* __restrict__ pos,
    float* __restrict__ out)
{
    int s = blockIdx.x, t = threadIdx.x;
    int r = s * 128 + t;
    const float4* p = (const float4*)(part + ((size_t)r << 6));
    float sum = 0.f;
    #pragma unroll
    for (int i = 0; i < 16; ++i) {
        float4 v = p[i];
        sum += v.x + v.y + v.z + v.w;
    }
    float val = logf(sum) - 2.0f * pos[r & (NB - 1)];
    #pragma unroll
    for (int off = 32; off >= 1; off >>= 1) val += __shfl_xor(val, off, 64);
    __shared__ float red[2];
    if ((t & 63) == 0) red[t >> 6] = val;
    __syncthreads();
    if (t == 0)
        atomicAdd(out, (red[0] + red[1]) * (1.0f / (float)TWO_N));
}

// ---------------------------------------------------------------------------
extern "C" void kernel_launch(void* const* d_in, const int* in_sizes, int n_in,
                              void* d_out, int out_size, void* d_ws, size_t ws_size,
                              hipStream_t stream)
{
    const float* emb_i = (const float*)d_in[0];
    const float* emb_j = (const float*)d_in[1];
    float* out = (float*)d_out;

    short* zt = (short*)d_ws;                             // 4096*256 bf16 = 2 MB (tiled)
    float* part = (float*)((char*)d_ws + (size_t)TWO_N * DIM * sizeof(short));
    // part: 4096 rows x 64 partials = 1 MB
    float* pos = part + (size_t)TWO_N * 64;               // 2048 f32

    nrm_kernel<<<NB / 4, 256, 0, stream>>>(emb_i, emb_j, zt, pos, out);
    simexp_kernel<<<NTILES, 256, 0, stream>>>(zt, part);
    redloss_kernel<<<NT1D, 128, 0, stream>>>(part, pos, out);
}

// Round 13
// 73.751 us; speedup vs baseline: 1.0097x; 1.0093x over previous
//
#include <hip/hip_runtime.h>
#include <hip/hip_bf16.h>
#include <math.h>

// Problem constants (reference: BATCH=2048, D=256, TEMP=0.5)
#define NB        2048
#define TWO_N     4096
#define DIM       256
#define EPS       1e-12f
#define NT1D      (TWO_N / 128)                 // 32 tile rows/cols
#define NTILES    (NT1D * (NT1D + 1) / 2)       // 528 upper-triangle tiles

// z storage: FRAGMENT-MAJOR tiled layout (r6). For row R, element e:
//   short_idx = (R>>4)*4096 + (e>>5)*512 + ((e>>3)&3)*128 + (R&15)*8 + (e&7)
// A (row-block RB, K-step s) fragment piece = 1 KB contiguous at
// RB*4096 + s*512; lane l's 16 B at +l*8 shorts.

typedef __attribute__((ext_vector_type(8))) short  bf16x8;   // 8 bf16 = 4 VGPRs
typedef __attribute__((ext_vector_type(4))) float  f32x4;    // MFMA C/D

// ---------------------------------------------------------------------------
// K1: one wave per PAIR r in [0,2048): L2-normalize emb_i[r] -> z[r] and
// emb_j[r] -> z[r+NB] (bf16, fragment-major layout), and write the
// fp32-exact positive dot pos[r] = <z_i, z_j>. Also zeroes the output.
// ---------------------------------------------------------------------------
__global__ __launch_bounds__(256) void nrm_kernel(
    const float* __restrict__ emb_i, const float* __restrict__ emb_j,
    short* __restrict__ zt, float* __restrict__ pos,
    float* __restrict__ out)
{
    int t = threadIdx.x;
    int wave = t >> 6, lane = t & 63;
    int r = blockIdx.x * 4 + wave;              // pair index 0..2047
    float4 a = ((const float4*)(emb_i + (size_t)r * DIM))[lane];
    float4 b = ((const float4*)(emb_j + (size_t)r * DIM))[lane];
    float sa = a.x*a.x + a.y*a.y + a.z*a.z + a.w*a.w;
    float sb = b.x*b.x + b.y*b.y + b.z*b.z + b.w*b.w;
    float sd = a.x*b.x + a.y*b.y + a.z*b.z + a.w*b.w;
    #pragma unroll
    for (int off = 32; off >= 1; off >>= 1) {
        sa += __shfl_xor(sa, off, 64);
        sb += __shfl_xor(sb, off, 64);
        sd += __shfl_xor(sd, off, 64);
    }
    float si = 1.0f / fmaxf(sqrtf(sa), EPS);
    float sj = 1.0f / fmaxf(sqrtf(sb), EPS);

    int dst = (r >> 4) * 4096 + (lane >> 3) * 512 + ((lane >> 1) & 3) * 128
            + (r & 15) * 8 + (lane & 1) * 4;

    union { __hip_bfloat16 h[4]; uint2 u; } pk;
    pk.h[0] = __float2bfloat16(a.x * si);
    pk.h[1] = __float2bfloat16(a.y * si);
    pk.h[2] = __float2bfloat16(a.z * si);
    pk.h[3] = __float2bfloat16(a.w * si);
    *(uint2*)(zt + dst) = pk.u;                       // z_i row r
    pk.h[0] = __float2bfloat16(b.x * sj);
    pk.h[1] = __float2bfloat16(b.y * sj);
    pk.h[2] = __float2bfloat16(b.z * sj);
    pk.h[3] = __float2bfloat16(b.w * sj);
    *(uint2*)(zt + dst + 128 * 4096) = pk.u;          // z_j row r+2048

    if (lane == 0) pos[r] = sd * si * sj;
    if (blockIdx.x == 0 && t == 0) out[0] = 0.0f;     // loss accumulator
}

// ---------------------------------------------------------------------------
// K2: bf16 MFMA over the 528 upper-triangle 128x128 tiles.
// r13 CHANGE: staging via __builtin_amdgcn_global_load_lds (direct
// global->LDS DMA, no VGPR round-trip).  Evidence: r2 VGPR=72, r8 VGPR=92 —
// the compiler demotes/remats register-staged G-sets for this code shape
// (demand ~180 > (256,3) cap ~170), re-serializing staging at full latency
// no matter the source schedule (r10==r11==r12).  global_load_lds removes
// the staged values from the register file entirely (demand ~130, no
// spill) and enables TRUE depth-2 prefetch:
//   - tri-buffered LDS: 3 x 16 KB = 48 KB (still 3 blocks/CU)
//   - chunk c: issue c+2 -> buf (c+2)%3, COMPUTE(c), then
//     s_waitcnt vmcnt(4)  (c+1's 4 loads done; c+2's may fly)  + raw
//     barrier (lgkmcnt(0) only — no vmcnt(0) drain, r12's BAR).
// HW fit: gload_lds writes LDS at uniform_base + lane*16B; our piece layout
// is exactly lds[bs*8192 + piece*512 + lane*8] with per-lane global src
// stg_base + l8 (contiguous 1 KB) — same bytes to same slots as r12 ->
// same MFMA order -> bit-identical accumulators.
// part[] slot scheme unchanged (round-2 comment).
// Fragment layouts (verified m89/m91): A[m=lane&15][k=quad*8+j],
// B[k=quad*8+j][n=lane&15], C/D: col=lane&15, row=quad*4+reg.
// ---------------------------------------------------------------------------
#define MFMA1(Av, Bv, m, n) \
    acc[m][n] = __builtin_amdgcn_mfma_f32_16x16x32_bf16(Av, Bv, acc[m][n], 0, 0, 0);

#define MFMA_ROW(Av, B0v, B1v, B2v, B3v, m) \
    MFMA1(Av, B0v, m, 0) MFMA1(Av, B1v, m, 1) \
    MFMA1(Av, B2v, m, 2) MFMA1(Av, B3v, m, 3)

#define MMSTEP(A0v, A1v, A2v, A3v, B0v, B1v, B2v, B3v) \
    MFMA_ROW(A0v, B0v, B1v, B2v, B3v, 0) \
    MFMA_ROW(A1v, B0v, B1v, B2v, B3v, 1) \
    MFMA_ROW(A2v, B0v, B1v, B2v, B3v, 2) \
    MFMA_ROW(A3v, B0v, B1v, B2v, B3v, 3)

#define SB __builtin_amdgcn_sched_barrier(0);

// Counted VMEM wait (inline asm; rule-#18 sched fences).
#define WAITV(n) \
    SB asm volatile("s_waitcnt vmcnt(" #n ")" ::: "memory"); SB

// Raw barrier: LDS-drain only (no vmcnt(0) drain).
#define BAR \
    SB asm volatile("s_waitcnt lgkmcnt(0)" ::: "memory"); SB \
    __builtin_amdgcn_s_barrier(); SB

// Direct global->LDS 16-B/lane load. LDS dest = uniform base (+lane*16 by HW).
#define GLOAD(gsrc, ldst) \
    __builtin_amdgcn_global_load_lds( \
        (const __attribute__((address_space(1))) void*)(gsrc), \
        (__attribute__((address_space(3))) void*)(ldst), 16, 0, 0);

// Issue the 4 piece-loads for chunk c into LDS buffer bs.
#define STAGE(c, bs) \
    GLOAD(stg_base + 0 * 4096 + (c) * 512, &lds[(bs)*8192 + (p0+0)*512]) \
    GLOAD(stg_base + 1 * 4096 + (c) * 512, &lds[(bs)*8192 + (p0+1)*512]) \
    GLOAD(stg_base + 2 * 4096 + (c) * 512, &lds[(bs)*8192 + (p0+2)*512]) \
    GLOAD(stg_base + 3 * 4096 + (c) * 512, &lds[(bs)*8192 + (p0+3)*512])

// One K-step from chunk buffer bs: 8 ds_read_b128 + 16 MFMA.
#define COMPUTE(bs) \
    { \
        bf16x8 fa0 = *(const bf16x8*)&lds[(bs)*8192 + (wm4+0)*512 + l8]; \
        bf16x8 fa1 = *(const bf16x8*)&lds[(bs)*8192 + (wm4+1)*512 + l8]; \
        bf16x8 fa2 = *(const bf16x8*)&lds[(bs)*8192 + (wm4+2)*512 + l8]; \
        bf16x8 fa3 = *(const bf16x8*)&lds[(bs)*8192 + (wm4+3)*512 + l8]; \
        bf16x8 fb0 = *(const bf16x8*)&lds[(bs)*8192 + 4096 + (wn4+0)*512 + l8]; \
        bf16x8 fb1 = *(const bf16x8*)&lds[(bs)*8192 + 4096 + (wn4+1)*512 + l8]; \
        bf16x8 fb2 = *(const bf16x8*)&lds[(bs)*8192 + 4096 + (wn4+2)*512 + l8]; \
        bf16x8 fb3 = *(const bf16x8*)&lds[(bs)*8192 + 4096 + (wn4+3)*512 + l8]; \
        MMSTEP(fa0, fa1, fa2, fa3, fb0, fb1, fb2, fb3) \
    }

__global__ __launch_bounds__(256, 3) void simexp_kernel(
    const short* __restrict__ zt, float* __restrict__ part)
{
    __shared__ short lds[3 * 8192];             // 3 x 16 KB chunk buffers

    // Decode linear triangle index -> (bx, by), bx <= by.
    int id = blockIdx.x;
    int by = (int)((sqrtf(8.0f * (float)id + 1.0f) - 1.0f) * 0.5f);
    while ((by + 1) * (by + 2) / 2 <= id) ++by;   // fix float rounding
    while (by * (by + 1) / 2 > id) --by;
    int bx = id - by * (by + 1) / 2;

    int t = threadIdx.x;
    int w = t >> 6, lane = t & 63;
    int quad = lane >> 4, c16 = lane & 15;
    int wm = w >> 1, wn = w & 1;
    int wm4 = wm * 4, wn4 = wn * 4;
    int l8 = lane * 8;
    int p0 = w * 4;
    int rbase = bx * 128 + wm * 64;
    int jbase = by * 128 + wn * 64;

    // Staging source: waves 0,1 -> A panel (row-blocks bx*8 + {0-3,4-7});
    // waves 2,3 -> B panel (by*8 + {0-3,4-7}). Includes per-lane l8.
    const short* stg_base = zt
        + (size_t)((w < 2 ? bx : by) * 8 + (w & 1) * 4) * 4096 + l8;

    f32x4 acc[4][4];
    #pragma unroll
    for (int mt = 0; mt < 4; ++mt)
        #pragma unroll
        for (int nt = 0; nt < 4; ++nt)
            acc[mt][nt] = (f32x4){0.f, 0.f, 0.f, 0.f};

    // Chunk c lives in buf c%3. Each wave issues exactly 4 loads/chunk, so
    // after STAGE(c+2) outstanding = {c+1: 4, c+2: 4}; vmcnt(4) = c+1 done.
    STAGE(0, 0)
    STAGE(1, 1)
    WAITV(4)            // chunk 0 resident
    BAR
    // chunk 0
    STAGE(2, 2)
    COMPUTE(0)
    WAITV(4)            // chunk 1 resident (chunk 2's loads still in flight)
    BAR
    // chunk 1
    STAGE(3, 0)
    COMPUTE(1)
    WAITV(4)
    BAR
    // chunk 2
    STAGE(4, 1)
    COMPUTE(2)
    WAITV(4)
    BAR
    // chunk 3
    STAGE(5, 2)
    COMPUTE(0)
    WAITV(4)
    BAR
    // chunk 4
    STAGE(6, 0)
    COMPUTE(1)
    WAITV(4)
    BAR
    // chunk 5
    STAGE(7, 1)
    COMPUTE(2)
    WAITV(4)
    BAR
    // chunk 6
    COMPUTE(0)
    WAITV(0)            // chunk 7 resident
    BAR
    // chunk 7
    COMPUTE(1)

    // Epilogue. Row of acc[mt][nt][rg] = rbase+mt*16+quad*4+rg,
    // col = jbase+nt*16+c16.
    float rsum[4][4];
    #pragma unroll
    for (int mt = 0; mt < 4; ++mt)
        #pragma unroll
        for (int rg = 0; rg < 4; ++rg) rsum[mt][rg] = 0.f;

    if (bx == by) {
        #pragma unroll
        for (int mt = 0; mt < 4; ++mt) {
            #pragma unroll
            for (int nt = 0; nt < 4; ++nt) {
                int j = jbase + nt * 16 + c16;
                #pragma unroll
                for (int rg = 0; rg < 4; ++rg) {
                    int r = rbase + mt * 16 + quad * 4 + rg;
                    float e = __expf(2.0f * acc[mt][nt][rg]);
                    rsum[mt][rg] += (r == j) ? 0.f : e;
                }
            }
        }
    } else {
        float csum[4] = {0.f, 0.f, 0.f, 0.f};
        #pragma unroll
        for (int mt = 0; mt < 4; ++mt) {
            #pragma unroll
            for (int nt = 0; nt < 4; ++nt) {
                #pragma unroll
                for (int rg = 0; rg < 4; ++rg) {
                    float e = __expf(2.0f * acc[mt][nt][rg]);
                    rsum[mt][rg] += e;
                    csum[nt] += e;
                }
            }
        }
        #pragma unroll
        for (int nt = 0; nt < 4; ++nt) {
            float v = csum[nt];
            v += __shfl_xor(v, 16, 64);
            v += __shfl_xor(v, 32, 64);
            if (quad == 0)
                part[(size_t)(by * 128 + wn * 64 + nt * 16 + c16) * 64
                     + 2 * bx + wm] = v;
        }
    }

    #pragma unroll
    for (int mt = 0; mt < 4; ++mt) {
        #pragma unroll
        for (int rg = 0; rg < 4; ++rg) {
            float v = rsum[mt][rg];
            v += __shfl_xor(v, 1, 64);
            v += __shfl_xor(v, 2, 64);
            v += __shfl_xor(v, 4, 64);
            v += __shfl_xor(v, 8, 64);
            if (c16 == 0)
                part[(size_t)(rbase + mt * 16 + quad * 4 + rg) * 64
                     + 2 * by + wn] = v;
        }
    }
}

// ---------------------------------------------------------------------------
// K3: 32 blocks x 128 threads. Block s, thread t owns row r = s*128+t:
// den_r = sum of its 64 partials (256 B contiguous), then
// loss_r = log(den_r) - 2*pos[r mod 2048]. Block-reduce, one atomicAdd of
// the scaled partial into out[0] (32 atomics total; out zeroed by K1).
// ---------------------------------------------------------------------------
__global__ __launch_bounds__(128) void redloss_kernel(
    const float* __restrict__ part, const float* __restrict__ pos,
    float* __restrict__ out)
{
    int s = blockIdx.x, t = threadIdx.x;
    int r = s * 128 + t;
    const float4* p = (const float4*)(part + ((size_t)r << 6));
    float sum = 0.f;
    #pragma unroll
    for (int i = 0; i < 16; ++i) {
        float4 v = p[i];
        sum += v.x + v.y + v.z + v.w;
    }
    float val = logf(sum) - 2.0f * pos[r & (NB - 1)];
    #pragma unroll
    for (int off = 32; off >= 1; off >>= 1) val += __shfl_xor(val, off, 64);
    __shared__ float red[2];
    if ((t & 63) == 0) red[t >> 6] = val;
    __syncthreads();
    if (t == 0)
        atomicAdd(out, (red[0] + red[1]) * (1.0f / (float)TWO_N));
}

// ---------------------------------------------------------------------------
extern "C" void kernel_launch(void* const* d_in, const int* in_sizes, int n_in,
                              void* d_out, int out_size, void* d_ws, size_t ws_size,
                              hipStream_t stream)
{
    const float* emb_i = (const float*)d_in[0];
    const float* emb_j = (const float*)d_in[1];
    float* out = (float*)d_out;

    short* zt = (short*)d_ws;                             // 4096*256 bf16 = 2 MB (tiled)
    float* part = (float*)((char*)d_ws + (size_t)TWO_N * DIM * sizeof(short));
    // part: 4096 rows x 64 partials = 1 MB
    float* pos = part + (size_t)TWO_N * 64;               // 2048 f32

    nrm_kernel<<<NB / 4, 256, 0, stream>>>(emb_i, emb_j, zt, pos, out);
    simexp_kernel<<<NTILES, 256, 0, stream>>>(zt, part);
    redloss_kernel<<<NT1D, 128, 0, stream>>>(part, pos, out);
}